// Round 2
// baseline (112.178 us; speedup 1.0000x reference)
//
#include <hip/hip_runtime.h>
#include <hip/hip_cooperative_groups.h>

namespace cg = cooperative_groups;

#define BN 512
#define DIM 128
#define TMARGIN 0.3f
#define NT 512
#define NW 8      // waves per block
#define NBLK 256  // 2 anchors per block, 1 block/CU
#define BIGF 1e30f

#define FMA4(ACC, U, V)                                                \
    ACC.x += U.x * V.x; ACC.y += U.y * V.y;                            \
    ACC.z += U.z * V.z; ACC.w += U.w * V.w;

__device__ __forceinline__ float hsum4(float4 v) {
    return (v.x + v.y) + (v.z + v.w);
}

// ---------------------------------------------------------------------------
// Single COOPERATIVE kernel: 256 blocks x 512 threads (1 block/CU, 8 waves).
// Block b handles anchors b and b+256.
//
// vs previous version:
//  * finalize_kernel is GONE. Each block stores its partial, then
//    grid.sync(); block 0 / wave 0 reduces the 256 slots and writes out[0].
//    Removes one dependent dispatch + its graph round-trip.
//  * Everything else unchanged (it measured well):
//    - anchors in registers (kl-slice, 64 VGPR)
//    - negative mask folded into drow (1e30 sentinel; no labels in Phase B)
//    - positive DISTANCES compacted inline in Phase A
// ---------------------------------------------------------------------------
__global__ __launch_bounds__(NT, 1) void triplet_coop_kernel(
        const float* __restrict__ emb,
        const int* __restrict__ labels,
        float* __restrict__ psum,    // [NBLK] workspace
        float* __restrict__ pcnt,    // [NBLK] workspace
        float* __restrict__ out) {   // [1]
    const int ia   = blockIdx.x;         // anchor A
    const int ib   = blockIdx.x + NBLK;  // anchor B
    const int tid  = threadIdx.x;
    const int lane = tid & 63;
    const int wave = tid >> 6;
    const int rl   = lane >> 2;   // row-in-group 0..15
    const int kl   = lane & 3;    // k-lane 0..3

    __shared__ float drowA[BN], drowB[BN];   // negatives-only distance rows
    __shared__ float pdA[BN], pdB[BN];       // positive distances (compact)
    __shared__ int   nposA, nposB;
    __shared__ float wsum[NW];
    __shared__ int   wcnt[NW];

    const float4* emb4 = (const float4*)emb;
    const int liA = labels[ia];
    const int liB = labels[ib];

    // --- anchor fragments in registers (kl-slice only) --------------------
    float4 ra[8], rb[8];
#pragma unroll
    for (int q = 0; q < 8; ++q) {
        ra[q] = emb4[(size_t)ia * 32 + kl + 4 * q];
        rb[q] = emb4[(size_t)ib * 32 + kl + 4 * q];
    }
    // squared norms: per-thread partial over the kl-slice, then 4-lane sum
    float4 sa = {0,0,0,0}, sb = {0,0,0,0};
#pragma unroll
    for (int q = 0; q < 8; ++q) { FMA4(sa, ra[q], ra[q]); FMA4(sb, rb[q], rb[q]); }
    float sqA = hsum4(sa), sqB = hsum4(sb);
    sqA += __shfl_xor(sqA, 1); sqA += __shfl_xor(sqA, 2);
    sqB += __shfl_xor(sqB, 1); sqB += __shfl_xor(sqB, 2);

    if (tid == 0) { nposA = 0; nposB = 0; }
    __syncthreads();

    // ---------------- Phase A: both dist rows, one pass over emb ----------
    // 8 waves x 16 rows/iter; 4 lanes per row, 64 B contiguous per group.
#pragma unroll
    for (int c = 0; c < 4; ++c) {
        const int r = c * 128 + wave * 16 + rl;
        float4 da = {0,0,0,0}, db = {0,0,0,0}, qq = {0,0,0,0};
#pragma unroll
        for (int q = 0; q < 8; ++q) {
            const float4 v = emb4[(size_t)r * 32 + kl + 4 * q];
            FMA4(da, ra[q], v);
            FMA4(db, rb[q], v);
            FMA4(qq, v, v);
        }
        float dotA = hsum4(da), dotB = hsum4(db), sqj = hsum4(qq);
        dotA += __shfl_down(dotA, 1); dotA += __shfl_down(dotA, 2);
        dotB += __shfl_down(dotB, 1); dotB += __shfl_down(dotB, 2);
        sqj  += __shfl_down(sqj, 1);  sqj  += __shfl_down(sqj, 2);
        if (kl == 0) {
            const int   lr = labels[r];
            const float dA = sqrtf(fmaxf(sqA + sqj - 2.f * dotA, 1e-12f));
            const float dB = sqrtf(fmaxf(sqB + sqj - 2.f * dotB, 1e-12f));
            const bool  eqA = (lr == liA), eqB = (lr == liB);
            drowA[r] = eqA ? BIGF : dA;     // self has eqA -> excluded too
            drowB[r] = eqB ? BIGF : dB;
            if (eqA && r != ia) { int p = atomicAdd(&nposA, 1); pdA[p] = dA; }
            if (eqB && r != ib) { int p = atomicAdd(&nposB, 1); pdB[p] = dB; }
        }
    }
    __syncthreads();

    // ---------------- Phase B: waves 0-3 anchor A, 4-7 anchor B -----------
    const int grp  = wave >> 2;             // 0: A, 1: B
    const int wsub = wave & 3;
    const float* drow = grp ? drowB : drowA;
    const float* pd   = grp ? pdB   : pdA;
    const int    npos = grp ? nposB : nposA;

    // min over negatives (BIGF is identity); has_neg == (mn < 1e29)
    float mn = BIGF;
#pragma unroll
    for (int kk = 0; kk < BN / 64; ++kk)
        mn = fminf(mn, drow[lane + 64 * kk]);
#pragma unroll
    for (int off = 32; off; off >>= 1)
        mn = fminf(mn, __shfl_xor(mn, off));

    float lsum = 0.f;
    int   lcnt = 0;
    if (mn < 1e29f) {
        for (int p = wsub; p < npos; p += 4) {
            const float dap = pd[p];
            const float hi  = dap + TMARGIN;
            float smax = -BIGF;
#pragma unroll
            for (int kk = 0; kk < BN / 64; ++kk) {
                const float dan = drow[lane + 64 * kk];
                if (dan > dap && dan < hi) smax = fmaxf(smax, dan);
            }
#pragma unroll
            for (int off = 32; off; off >>= 1)
                smax = fmaxf(smax, __shfl_xor(smax, off));
            const float dneg = (smax > -1e29f) ? smax : mn;
            lsum += fmaxf(dap - dneg + TMARGIN, 0.f);
            lcnt += 1;
        }
    }
    if (lane == 0) { wsum[wave] = lsum; wcnt[wave] = lcnt; }
    __syncthreads();

    // one combined partial per block; device-visible before grid sync
    if (tid == 0) {
        float s = 0.f;
        int   c = 0;
#pragma unroll
        for (int w = 0; w < NW; ++w) { s += wsum[w]; c += wcnt[w]; }
        psum[blockIdx.x] = s;
        pcnt[blockIdx.x] = (float)c;
        __threadfence();   // device-scope release (cross-XCD visibility)
    }

    cg::this_grid().sync();

    // ---------------- grid epilogue: block 0, wave 0 ----------------------
    if (blockIdx.x == 0 && wave == 0) {
        float s = 0.f, c = 0.f;
#pragma unroll
        for (int i = 0; i < NBLK / 64; ++i) {
            s += psum[lane + 64 * i];
            c += pcnt[lane + 64 * i];
        }
#pragma unroll
        for (int off = 32; off; off >>= 1) {
            s += __shfl_xor(s, off);
            c += __shfl_xor(c, off);
        }
        if (lane == 0)
            out[0] = (c > 0.f) ? (s / fmaxf(c, 1.f)) : 0.f;
    }
}

extern "C" void kernel_launch(void* const* d_in, const int* in_sizes, int n_in,
                              void* d_out, int out_size, void* d_ws, size_t ws_size,
                              hipStream_t stream) {
    const float* emb    = (const float*)d_in[0];
    const int*   labels = (const int*)d_in[1];
    float*       out    = (float*)d_out;
    float*       psum   = (float*)d_ws;        // [256]
    float*       pcnt   = psum + NBLK;         // [256]

    void* args[] = { (void*)&emb, (void*)&labels, (void*)&psum,
                     (void*)&pcnt, (void*)&out };
    hipLaunchCooperativeKernel((const void*)triplet_coop_kernel,
                               dim3(NBLK), dim3(NT), args, 0, stream);
}

// Round 3
// 63.911 us; speedup vs baseline: 1.7552x; 1.7552x over previous
//
#include <hip/hip_runtime.h>

#define BN 512
#define DIM 128
#define TMARGIN 0.3f
#define NT 1024
#define NW 16     // waves per block
#define NBLK 256  // 2 anchors per block, 1 block/CU
#define BIGF 1e30f

#define FMA4(ACC, U, V)                                                \
    ACC.x += U.x * V.x; ACC.y += U.y * V.y;                            \
    ACC.z += U.z * V.z; ACC.w += U.w * V.w;

__device__ __forceinline__ float hsum4(float4 v) {
    return (v.x + v.y) + (v.z + v.w);
}

// ---------------------------------------------------------------------------
// REVERTED to the two-kernel structure (round-1, 66.2 us): cooperative
// grid.sync() cost ~20+ us in-kernel AND lost the graph-launch fast path
// (round-2 post-mortem: fused kernel 40 us, total 112 us).
//
// vs round-1 version (one change): NT 512 -> 1024 (16 waves, 4 waves/SIMD).
// The kernel is latency-bound, not pipe-bound (VALUBusy ~8%, HBM ~0%): same
// total work spread over 2x waves halves Phase A's per-thread load depth
// (32 -> 16 L2-hit loads) and doubles latency hiding. VGPR=68 fits 4
// waves/SIMD (<=128) with room.
//
// Retained (all measured wins):
//  * anchors in registers (kl-slice, 64 VGPR)
//  * negative mask folded into drow (1e30 sentinel; no labels in Phase B)
//  * positive DISTANCES compacted inline in Phase A
//  * one plain-store partial per block; tiny 1-wave finalize kernel
// ---------------------------------------------------------------------------
__global__ __launch_bounds__(NT, 4) void triplet_fused_kernel(
        const float* __restrict__ emb,
        const int* __restrict__ labels,
        float* __restrict__ psum,    // [NBLK]
        float* __restrict__ pcnt) {  // [NBLK]
    const int ia   = blockIdx.x;         // anchor A
    const int ib   = blockIdx.x + NBLK;  // anchor B
    const int tid  = threadIdx.x;
    const int lane = tid & 63;
    const int wave = tid >> 6;
    const int rl   = lane >> 2;   // row-in-group 0..15
    const int kl   = lane & 3;    // k-lane 0..3

    __shared__ float drowA[BN], drowB[BN];   // negatives-only distance rows
    __shared__ float pdA[BN], pdB[BN];       // positive distances (compact)
    __shared__ int   nposA, nposB;
    __shared__ float wsum[NW];
    __shared__ int   wcnt[NW];

    const float4* emb4 = (const float4*)emb;
    const int liA = labels[ia];
    const int liB = labels[ib];

    // --- anchor fragments in registers (kl-slice only) --------------------
    float4 ra[8], rb[8];
#pragma unroll
    for (int q = 0; q < 8; ++q) {
        ra[q] = emb4[(size_t)ia * 32 + kl + 4 * q];
        rb[q] = emb4[(size_t)ib * 32 + kl + 4 * q];
    }
    // squared norms: per-thread partial over the kl-slice, then 4-lane sum
    float4 sa = {0,0,0,0}, sb = {0,0,0,0};
#pragma unroll
    for (int q = 0; q < 8; ++q) { FMA4(sa, ra[q], ra[q]); FMA4(sb, rb[q], rb[q]); }
    float sqA = hsum4(sa), sqB = hsum4(sb);
    sqA += __shfl_xor(sqA, 1); sqA += __shfl_xor(sqA, 2);
    sqB += __shfl_xor(sqB, 1); sqB += __shfl_xor(sqB, 2);

    if (tid == 0) { nposA = 0; nposB = 0; }
    __syncthreads();

    // ---------------- Phase A: both dist rows, one pass over emb ----------
    // 16 waves x 16 rows/iter; 4 lanes per row, 64 B contiguous per group.
#pragma unroll
    for (int c = 0; c < 2; ++c) {
        const int r = c * 256 + wave * 16 + rl;
        float4 da = {0,0,0,0}, db = {0,0,0,0}, qq = {0,0,0,0};
#pragma unroll
        for (int q = 0; q < 8; ++q) {
            const float4 v = emb4[(size_t)r * 32 + kl + 4 * q];
            FMA4(da, ra[q], v);
            FMA4(db, rb[q], v);
            FMA4(qq, v, v);
        }
        float dotA = hsum4(da), dotB = hsum4(db), sqj = hsum4(qq);
        dotA += __shfl_down(dotA, 1); dotA += __shfl_down(dotA, 2);
        dotB += __shfl_down(dotB, 1); dotB += __shfl_down(dotB, 2);
        sqj  += __shfl_down(sqj, 1);  sqj  += __shfl_down(sqj, 2);
        if (kl == 0) {
            const int   lr = labels[r];
            const float dA = sqrtf(fmaxf(sqA + sqj - 2.f * dotA, 1e-12f));
            const float dB = sqrtf(fmaxf(sqB + sqj - 2.f * dotB, 1e-12f));
            const bool  eqA = (lr == liA), eqB = (lr == liB);
            drowA[r] = eqA ? BIGF : dA;     // self has eqA -> excluded too
            drowB[r] = eqB ? BIGF : dB;
            if (eqA && r != ia) { int p = atomicAdd(&nposA, 1); pdA[p] = dA; }
            if (eqB && r != ib) { int p = atomicAdd(&nposB, 1); pdB[p] = dB; }
        }
    }
    __syncthreads();

    // ---------------- Phase B: waves 0-7 anchor A, 8-15 anchor B ----------
    const int grp  = wave >> 3;             // 0: A, 1: B
    const int wsub = wave & 7;
    const float* drow = grp ? drowB : drowA;
    const float* pd   = grp ? pdB   : pdA;
    const int    npos = grp ? nposB : nposA;

    // min over negatives (BIGF is identity); has_neg == (mn < 1e29)
    float mn = BIGF;
#pragma unroll
    for (int kk = 0; kk < BN / 64; ++kk)
        mn = fminf(mn, drow[lane + 64 * kk]);
#pragma unroll
    for (int off = 32; off; off >>= 1)
        mn = fminf(mn, __shfl_xor(mn, off));

    float lsum = 0.f;
    int   lcnt = 0;
    if (mn < 1e29f) {
        for (int p = wsub; p < npos; p += 8) {
            const float dap = pd[p];
            const float hi  = dap + TMARGIN;
            float smax = -BIGF;
#pragma unroll
            for (int kk = 0; kk < BN / 64; ++kk) {
                const float dan = drow[lane + 64 * kk];
                if (dan > dap && dan < hi) smax = fmaxf(smax, dan);
            }
#pragma unroll
            for (int off = 32; off; off >>= 1)
                smax = fmaxf(smax, __shfl_xor(smax, off));
            const float dneg = (smax > -1e29f) ? smax : mn;
            lsum += fmaxf(dap - dneg + TMARGIN, 0.f);
            lcnt += 1;
        }
    }
    if (lane == 0) { wsum[wave] = lsum; wcnt[wave] = lcnt; }
    __syncthreads();

    // one combined partial per block; plain stores (kernel-end flush)
    if (tid == 0) {
        float s = 0.f;
        int   c = 0;
#pragma unroll
        for (int w = 0; w < NW; ++w) { s += wsum[w]; c += wcnt[w]; }
        psum[blockIdx.x] = s;
        pcnt[blockIdx.x] = (float)c;
    }
}

// ---------------------------------------------------------------------------
// Finalize: one wave reduces the 256 partial slots. No LDS, no barriers.
// ---------------------------------------------------------------------------
__global__ __launch_bounds__(64) void finalize_kernel(
        const float* __restrict__ psum,
        const float* __restrict__ pcnt,
        float* __restrict__ out) {
    const int lane = threadIdx.x;
    float s = 0.f, c = 0.f;
#pragma unroll
    for (int i = 0; i < 4; ++i) {
        s += psum[lane + 64 * i];
        c += pcnt[lane + 64 * i];
    }
#pragma unroll
    for (int off = 32; off; off >>= 1) {
        s += __shfl_xor(s, off);
        c += __shfl_xor(c, off);
    }
    if (lane == 0)
        out[0] = (c > 0.f) ? (s / fmaxf(c, 1.f)) : 0.f;
}

extern "C" void kernel_launch(void* const* d_in, const int* in_sizes, int n_in,
                              void* d_out, int out_size, void* d_ws, size_t ws_size,
                              hipStream_t stream) {
    const float* emb    = (const float*)d_in[0];
    const int*   labels = (const int*)d_in[1];
    float*       out    = (float*)d_out;
    float*       psum   = (float*)d_ws;        // [256]
    float*       pcnt   = psum + NBLK;         // [256]

    triplet_fused_kernel<<<NBLK, NT, 0, stream>>>(emb, labels, psum, pcnt);
    finalize_kernel<<<1, 64, 0, stream>>>(psum, pcnt, out);
}